// Round 6
// baseline (195.404 us; speedup 1.0000x reference)
//
#include <hip/hip_runtime.h>
#include <math.h>

#define NNODES 100000
#define NEDGES 3200000
#define NF 128
#define NH 16
#define SB 192                   // nodes per super-bucket
#define NSB 521                  // ceil(NNODES/SB)
#define NBLK 1024                // blocks for hist/scatter
#define EPB (NEDGES / NBLK)      // 3125 exact
#define CAP2 6912                // max edges/super-bucket (mean 6144, std ~78 -> +9.8 sigma)

__device__ __forceinline__ unsigned bf16rne(float f) {
    unsigned u = __float_as_uint(f);
    return (u + 0x7fffu + ((u >> 16) & 1u)) >> 16;
}

// ---------------- pass A: per-block super-bucket histogram -----------------
// ghist layout: [NBLK][NSB]  (block-contiguous)
__global__ void k_hist(const int* __restrict__ col, unsigned* __restrict__ ghist) {
    __shared__ unsigned h[NSB];
    int t = threadIdx.x, b = blockIdx.x;
    for (int i = t; i < NSB; i += 256) h[i] = 0u;
    __syncthreads();
    int e0 = b * EPB;
    for (int i = t; i < EPB; i += 256)
        atomicAdd(&h[(unsigned)col[e0 + i] / SB], 1u);
    __syncthreads();
    for (int i = t; i < NSB; i += 256) ghist[(size_t)b * NSB + i] = h[i];
}

// ---------------- scan 1: per-bucket exclusive scan across blocks ----------
__global__ __launch_bounds__(NBLK) void k_scan1(unsigned* __restrict__ ghist,
                                                unsigned* __restrict__ totals) {
    int k = blockIdx.x, t = threadIdx.x;
    __shared__ unsigned s[NBLK];
    unsigned v = ghist[(size_t)t * NSB + k];
    s[t] = v;
    __syncthreads();
    for (int off = 1; off < NBLK; off <<= 1) {
        unsigned x = (t >= off) ? s[t - off] : 0u;
        __syncthreads();
        s[t] += x;
        __syncthreads();
    }
    ghist[(size_t)t * NSB + k] = s[t] - v;  // exclusive intra-bucket offset per block
    if (t == NBLK - 1) totals[k] = s[t];
}

// ---------------- scan 2: exclusive scan of bucket totals -> sbase ---------
__global__ void k_scan2(const unsigned* __restrict__ totals, unsigned* __restrict__ sbase,
                        unsigned* __restrict__ start) {
    int t = threadIdx.x;
    __shared__ unsigned s[256];
    unsigned v[3];
    unsigned p = 0;
#pragma unroll
    for (int j = 0; j < 3; ++j) {
        int i = t * 3 + j;
        v[j] = (i < NSB) ? totals[i] : 0u;
        p += v[j];
    }
    s[t] = p;
    __syncthreads();
    for (int off = 1; off < 256; off <<= 1) {
        unsigned x = (t >= off) ? s[t - off] : 0u;
        __syncthreads();
        s[t] += x;
        __syncthreads();
    }
    unsigned run = s[t] - p;
#pragma unroll
    for (int j = 0; j < 3; ++j) {
        int i = t * 3 + j;
        if (i < NSB) sbase[i] = run;
        run += v[j];
    }
    if (t == 255) { sbase[NSB] = NEDGES; start[NNODES] = NEDGES; }
}

// ---------------- pass B: scatter edges to super-bucket order (8B packed) --
__global__ void k_scatB1(const int* __restrict__ row, const int* __restrict__ col,
                         const float* __restrict__ ew,
                         const unsigned* __restrict__ ghist, const unsigned* __restrict__ sbase,
                         uint2* __restrict__ spack) {
    __shared__ unsigned cnt[NSB];
    int t = threadIdx.x, b = blockIdx.x;
    for (int i = t; i < NSB; i += 256) cnt[i] = sbase[i] + ghist[(size_t)b * NSB + i];
    __syncthreads();
    int e0 = b * EPB;
    for (int i = t; i < EPB; i += 256) {
        int e = e0 + i;
        unsigned r = (unsigned)row[e];
        unsigned c = (unsigned)col[e];
        float w = ew[e];
        unsigned sb = c / SB;
        unsigned ln = c - sb * SB;
        unsigned pos = atomicAdd(&cnt[sb], 1u);
        spack[pos] = make_uint2(r | (ln << 17), __float_as_uint(w));
    }
}

// ------- per-super-bucket LDS sort to node (CSR) order, in place -----------
// also computes weighted in-degree -> dinv and per-node CSR start offsets
__global__ __launch_bounds__(256) void k_sortB2(uint2* __restrict__ spack,
                                                const unsigned* __restrict__ sbase,
                                                unsigned* __restrict__ start,
                                                float* __restrict__ dinv) {
    __shared__ uint2 ed[CAP2];        // 55.3 KB
    __shared__ unsigned hist[SB];
    __shared__ float wdeg[SB];
    __shared__ unsigned scn[256];
    int k = blockIdx.x, t = threadIdx.x;
    unsigned e0 = sbase[k], e1 = sbase[k + 1];
    int ne = (int)(e1 - e0);
    if (t < SB) { hist[t] = 0u; wdeg[t] = 0.f; }
    __syncthreads();
    for (int i = t; i < ne; i += 256) {   // stage + histogram
        uint2 p = spack[e0 + i];
        ed[i] = p;
        unsigned ln = p.x >> 17;
        atomicAdd(&hist[ln], 1u);
        atomicAdd(&wdeg[ln], __uint_as_float(p.y));
    }
    __syncthreads();
    unsigned v = (t < SB) ? hist[t] : 0u;
    scn[t] = v;
    __syncthreads();
    for (int off = 1; off < 256; off <<= 1) {
        unsigned x = (t >= off) ? scn[t - off] : 0u;
        __syncthreads();
        scn[t] += x;
        __syncthreads();
    }
    unsigned excl = scn[t] - v;
    int g = k * SB + t;
    if (t < SB && g < NNODES) {
        start[g] = e0 + excl;
        dinv[g] = rsqrtf(wdeg[t] + 1.0f);   // +1 = self-loop weight
    }
    __syncthreads();
    if (t < SB) hist[t] = excl;             // running write counters
    __syncthreads();
    for (int i = t; i < ne; i += 256) {     // write back in node order
        uint2 p = ed[i];
        unsigned ln = p.x >> 17;
        unsigned pos = atomicAdd(&hist[ln], 1u);
        spack[e0 + pos] = make_uint2(p.x & 0x1FFFF, p.y);
    }
}

// -------- xwn = bf16( (x @ W1) * dinv[i] )  [NNODES x 16, 3.2 MB] ----------
__global__ void k_xw1n(const float* __restrict__ x, const float* __restrict__ W1,
                       const float* __restrict__ dinv, unsigned* __restrict__ xwn) {
    __shared__ float w[NF * NH];
    for (int t = threadIdx.x; t < NF * NH; t += blockDim.x) w[t] = W1[t];
    __syncthreads();
    int i = blockIdx.x * blockDim.x + threadIdx.x;
    if (i >= NNODES) return;
    float acc[NH];
#pragma unroll
    for (int f = 0; f < NH; ++f) acc[f] = 0.f;
    const float4* xr = (const float4*)(x + (long long)i * NF);
#pragma unroll 8
    for (int k4 = 0; k4 < NF / 4; ++k4) {
        float4 v = xr[k4];
        const float* wk = &w[k4 * 4 * NH];
#pragma unroll
        for (int f = 0; f < NH; ++f)
            acc[f] += v.x * wk[f] + v.y * wk[NH + f] + v.z * wk[2 * NH + f] + v.w * wk[3 * NH + f];
    }
    float di = dinv[i];
    unsigned u[8];
#pragma unroll
    for (int j = 0; j < 8; ++j)
        u[j] = bf16rne(acc[2 * j] * di) | (bf16rne(acc[2 * j + 1] * di) << 16);
    uint4* o = (uint4*)(xwn + (size_t)i * 8);
    o[0] = make_uint4(u[0], u[1], u[2], u[3]);
    o[1] = make_uint4(u[4], u[5], u[6], u[7]);
}

// ------- layer 1 pull: one wave/node, 4 lanes/edge (16 edges in flight) ----
__global__ __launch_bounds__(256) void k_edge1z(
        const uint2* __restrict__ spack, const unsigned* __restrict__ start,
        const unsigned* __restrict__ xwn, const float* __restrict__ dinv,
        const float* __restrict__ b1, const float* __restrict__ W2,
        float* __restrict__ zn) {
    int t = threadIdx.x;
    int n = blockIdx.x * 4 + (t >> 6);  // 25000 blocks * 4 waves = 100000
    int lane = t & 63;
    int fg = lane & 3, e4 = lane >> 2;
    unsigned e0 = start[n], e1 = start[n + 1];
    float ax = 0.f, ay = 0.f, az = 0.f, aw = 0.f;
    for (unsigned e = e0 + e4; e < e1; e += 16) {
        uint2 p = spack[e];
        uint2 q = *(const uint2*)(xwn + (size_t)p.x * 8 + fg * 2);
        float w = __uint_as_float(p.y);
        ax += __uint_as_float(q.x << 16) * w;
        ay += __uint_as_float(q.x & 0xffff0000u) * w;
        az += __uint_as_float(q.y << 16) * w;
        aw += __uint_as_float(q.y & 0xffff0000u) * w;
    }
#pragma unroll
    for (int m = 4; m < 64; m <<= 1) {
        ax += __shfl_xor(ax, m);
        ay += __shfl_xor(ay, m);
        az += __shfl_xor(az, m);
        aw += __shfl_xor(aw, m);
    }
    // self-loop (xwn already carries dinv[n])
    uint2 qs = *(const uint2*)(xwn + (size_t)n * 8 + fg * 2);
    ax += __uint_as_float(qs.x << 16);
    ay += __uint_as_float(qs.x & 0xffff0000u);
    az += __uint_as_float(qs.y << 16);
    aw += __uint_as_float(qs.y & 0xffff0000u);
    float di = dinv[n];
    float4 b4 = ((const float4*)b1)[fg];
    float4 w4 = ((const float4*)W2)[fg];
    float s = fmaxf(di * ax + b4.x, 0.f) * w4.x
            + fmaxf(di * ay + b4.y, 0.f) * w4.y
            + fmaxf(di * az + b4.z, 0.f) * w4.z
            + fmaxf(di * aw + b4.w, 0.f) * w4.w;
    s += __shfl_xor(s, 1);
    s += __shfl_xor(s, 2);
    if (lane == 0) zn[n] = s * di;   // store z * dinv for layer 2
}

// ------- layer 2 pull: one wave per node (64 edges in flight) --------------
__global__ __launch_bounds__(256) void k_edge2out(
        const uint2* __restrict__ spack, const unsigned* __restrict__ start,
        const float* __restrict__ zn, const float* __restrict__ dinv,
        const float* __restrict__ b2, float* __restrict__ out) {
    int t = threadIdx.x;
    int n = blockIdx.x * 4 + (t >> 6);  // 25000 blocks * 4 waves = 100000
    int lane = t & 63;
    unsigned e0 = start[n], e1 = start[n + 1];
    float acc = 0.f;
    for (unsigned e = e0 + lane; e < e1; e += 64) {
        uint2 p = spack[e];
        acc += zn[p.x] * __uint_as_float(p.y);
    }
#pragma unroll
    for (int m = 1; m < 64; m <<= 1) acc += __shfl_xor(acc, m);
    if (lane == 0) {
        float di = dinv[n];
        float v = di * acc + di * zn[n] + b2[0];
        out[n] = 1.f / (1.f + expf(-v));
    }
}

extern "C" void kernel_launch(void* const* d_in, const int* in_sizes, int n_in,
                              void* d_out, int out_size, void* d_ws, size_t ws_size,
                              hipStream_t stream) {
    const float* x  = (const float*)d_in[0];
    const int* eidx = (const int*)d_in[1];
    const float* ew = (const float*)d_in[2];
    const float* W1 = (const float*)d_in[3];
    const float* b1 = (const float*)d_in[4];
    const float* W2 = (const float*)d_in[5];
    const float* b2 = (const float*)d_in[6];
    float* out = (float*)d_out;

    const int* row = eidx;           // edge_index[0]
    const int* col = eidx + NEDGES;  // edge_index[1]

    // workspace layout (4-byte words), total ~32 MB
    unsigned* ws = (unsigned*)d_ws;
    uint2*    spack  = (uint2*)ws;                       // 3,200,000 x 8B
    unsigned* xwn    = ws + 6400000;                     //   800,000 (bf16 x 16/node)
    float*    dinv   = (float*)(ws + 7200000);           //   100,000
    float*    zn     = (float*)(ws + 7300000);           //   100,000
    unsigned* start  = ws + 7400000;                     //   100,001
    unsigned* sbase  = ws + 7500001;                     //       522
    unsigned* totals = ws + 7500523;                     //       521
    unsigned* ghist  = ws + 7501044;                     //   533,504 (NBLK*NSB)

    k_hist   <<<NBLK, 256, 0, stream>>>(col, ghist);
    k_scan1  <<<NSB, NBLK, 0, stream>>>(ghist, totals);
    k_scan2  <<<1, 256, 0, stream>>>(totals, sbase, start);
    k_scatB1 <<<NBLK, 256, 0, stream>>>(row, col, ew, ghist, sbase, spack);
    k_sortB2 <<<NSB, 256, 0, stream>>>(spack, sbase, start, dinv);
    k_xw1n   <<<(NNODES + 255) / 256, 256, 0, stream>>>(x, W1, dinv, xwn);
    k_edge1z <<<NNODES / 4, 256, 0, stream>>>(spack, start, xwn, dinv, b1, W2, zn);
    k_edge2out<<<NNODES / 4, 256, 0, stream>>>(spack, start, zn, dinv, b2, out);
}

// Round 7
// 178.051 us; speedup vs baseline: 1.0975x; 1.0975x over previous
//
#include <hip/hip_runtime.h>
#include <math.h>

#define NNODES 100000
#define NEDGES 3200000
#define NF 128
#define NH 16
#define SB 192                   // nodes per super-bucket
#define NSB 521                  // ceil(NNODES/SB)
#define NBLK 512                 // blocks for hist/scatter
#define EPB (NEDGES / NBLK)      // 6250 exact
#define CAP2 6912                // max edges/super-bucket (mean 6144, std ~78 -> +9.8 sigma)

__device__ __forceinline__ unsigned bf16rne(float f) {
    unsigned u = __float_as_uint(f);
    return (u + 0x7fffu + ((u >> 16) & 1u)) >> 16;
}

// ---------------- pass A: per-block super-bucket histogram -----------------
// ghist layout: [NBLK][NSB]  (block-contiguous)
__global__ void k_hist(const int* __restrict__ col, unsigned* __restrict__ ghist) {
    __shared__ unsigned h[NSB];
    int t = threadIdx.x, b = blockIdx.x;
    for (int i = t; i < NSB; i += 256) h[i] = 0u;
    __syncthreads();
    int e0 = b * EPB;
    for (int i = t; i < EPB; i += 256)
        atomicAdd(&h[(unsigned)col[e0 + i] / SB], 1u);
    __syncthreads();
    for (int i = t; i < NSB; i += 256) ghist[(size_t)b * NSB + i] = h[i];
}

// ---------------- scan 1: per-bucket exclusive scan across blocks ----------
__global__ __launch_bounds__(NBLK) void k_scan1(unsigned* __restrict__ ghist,
                                                unsigned* __restrict__ totals) {
    int k = blockIdx.x, t = threadIdx.x;
    __shared__ unsigned s[NBLK];
    unsigned v = ghist[(size_t)t * NSB + k];
    s[t] = v;
    __syncthreads();
    for (int off = 1; off < NBLK; off <<= 1) {
        unsigned x = (t >= off) ? s[t - off] : 0u;
        __syncthreads();
        s[t] += x;
        __syncthreads();
    }
    ghist[(size_t)t * NSB + k] = s[t] - v;  // exclusive intra-bucket offset per block
    if (t == NBLK - 1) totals[k] = s[t];
}

// ---------------- scan 2: exclusive scan of bucket totals -> sbase ---------
__global__ void k_scan2(const unsigned* __restrict__ totals, unsigned* __restrict__ sbase,
                        unsigned* __restrict__ start) {
    int t = threadIdx.x;
    __shared__ unsigned s[256];
    unsigned v[3];
    unsigned p = 0;
#pragma unroll
    for (int j = 0; j < 3; ++j) {
        int i = t * 3 + j;
        v[j] = (i < NSB) ? totals[i] : 0u;
        p += v[j];
    }
    s[t] = p;
    __syncthreads();
    for (int off = 1; off < 256; off <<= 1) {
        unsigned x = (t >= off) ? s[t - off] : 0u;
        __syncthreads();
        s[t] += x;
        __syncthreads();
    }
    unsigned run = s[t] - p;
#pragma unroll
    for (int j = 0; j < 3; ++j) {
        int i = t * 3 + j;
        if (i < NSB) sbase[i] = run;
        run += v[j];
    }
    if (t == 255) { sbase[NSB] = NEDGES; start[NNODES] = NEDGES; }
}

// ------ pass B: write-coalesced scatter (LDS-staged, onesweep style) -------
__global__ __launch_bounds__(256) void k_scatB1(
        const int* __restrict__ row, const int* __restrict__ col,
        const float* __restrict__ ew,
        const unsigned* __restrict__ ghist, const unsigned* __restrict__ sbase,
        uint2* __restrict__ spack) {
    __shared__ uint2 stage[EPB];            // 50,000 B
    __shared__ unsigned short sbArr[EPB];   // 12,500 B
    __shared__ unsigned lcnt[NSB];          //  2,084 B  (hist -> run-start counters)
    __shared__ unsigned gdelta[NSB];        //  2,084 B  (global pos = i + gdelta[sb])
    __shared__ unsigned scn[256];           //  1,024 B
    int t = threadIdx.x, b = blockIdx.x;
    int e0 = b * EPB;
    for (int i = t; i < NSB; i += 256) lcnt[i] = 0u;
    __syncthreads();
    // local histogram
    for (int i = t; i < EPB; i += 256)
        atomicAdd(&lcnt[(unsigned)col[e0 + i] / SB], 1u);
    __syncthreads();
    // exclusive scan over NSB bins (3 per thread)
    unsigned v[3];
    unsigned p = 0;
#pragma unroll
    for (int j = 0; j < 3; ++j) {
        int i = t * 3 + j;
        v[j] = (i < NSB) ? lcnt[i] : 0u;
        p += v[j];
    }
    scn[t] = p;
    __syncthreads();
    for (int off = 1; off < 256; off <<= 1) {
        unsigned x = (t >= off) ? scn[t - off] : 0u;
        __syncthreads();
        scn[t] += x;
        __syncthreads();
    }
    unsigned run = scn[t] - p;
    __syncthreads();  // all reads of lcnt done before overwrite
    unsigned lst[3];
#pragma unroll
    for (int j = 0; j < 3; ++j) {
        int i = t * 3 + j;
        if (i < NSB) {
            lst[j] = run;
            gdelta[i] = sbase[i] + ghist[(size_t)b * NSB + i] - run;
        }
        run += v[j];
    }
    __syncthreads();
#pragma unroll
    for (int j = 0; j < 3; ++j) {
        int i = t * 3 + j;
        if (i < NSB) lcnt[i] = lst[j];
    }
    __syncthreads();
    // local scatter into LDS stage
    for (int i = t; i < EPB; i += 256) {
        int e = e0 + i;
        unsigned r = (unsigned)row[e];
        unsigned c = (unsigned)col[e];
        float w = ew[e];
        unsigned sb = c / SB;
        unsigned ln = c - sb * SB;
        unsigned pos = atomicAdd(&lcnt[sb], 1u);
        stage[pos] = make_uint2(r | (ln << 17), __float_as_uint(w));
        sbArr[pos] = (unsigned short)sb;
    }
    __syncthreads();
    // coalesced write-out: consecutive lanes -> consecutive global addresses
    for (int i = t; i < EPB; i += 256)
        spack[i + gdelta[sbArr[i]]] = stage[i];
}

// ------- per-super-bucket LDS sort to node (CSR) order, in place -----------
// also computes weighted in-degree -> dinv and per-node CSR start offsets
__global__ __launch_bounds__(256) void k_sortB2(uint2* __restrict__ spack,
                                                const unsigned* __restrict__ sbase,
                                                unsigned* __restrict__ start,
                                                float* __restrict__ dinv) {
    __shared__ uint2 ed[CAP2];        // 55.3 KB
    __shared__ unsigned hist[SB];
    __shared__ float wdeg[SB];
    __shared__ unsigned scn[256];
    int k = blockIdx.x, t = threadIdx.x;
    unsigned e0 = sbase[k], e1 = sbase[k + 1];
    int ne = (int)(e1 - e0);
    if (t < SB) { hist[t] = 0u; wdeg[t] = 0.f; }
    __syncthreads();
    for (int i = t; i < ne; i += 256) {   // stage + histogram
        uint2 p = spack[e0 + i];
        ed[i] = p;
        unsigned ln = p.x >> 17;
        atomicAdd(&hist[ln], 1u);
        atomicAdd(&wdeg[ln], __uint_as_float(p.y));
    }
    __syncthreads();
    unsigned v = (t < SB) ? hist[t] : 0u;
    scn[t] = v;
    __syncthreads();
    for (int off = 1; off < 256; off <<= 1) {
        unsigned x = (t >= off) ? scn[t - off] : 0u;
        __syncthreads();
        scn[t] += x;
        __syncthreads();
    }
    unsigned excl = scn[t] - v;
    int g = k * SB + t;
    if (t < SB && g < NNODES) {
        start[g] = e0 + excl;
        dinv[g] = rsqrtf(wdeg[t] + 1.0f);   // +1 = self-loop weight
    }
    __syncthreads();
    if (t < SB) hist[t] = excl;             // running write counters
    __syncthreads();
    for (int i = t; i < ne; i += 256) {     // write back in node order
        uint2 p = ed[i];
        unsigned ln = p.x >> 17;
        unsigned pos = atomicAdd(&hist[ln], 1u);
        spack[e0 + pos] = make_uint2(p.x & 0x1FFFF, p.y);
    }
}

// -------- xwn = bf16( (x @ W1) * dinv[i] )  [NNODES x 16, 3.2 MB] ----------
__global__ void k_xw1n(const float* __restrict__ x, const float* __restrict__ W1,
                       const float* __restrict__ dinv, unsigned* __restrict__ xwn) {
    __shared__ float w[NF * NH];
    for (int t = threadIdx.x; t < NF * NH; t += blockDim.x) w[t] = W1[t];
    __syncthreads();
    int i = blockIdx.x * blockDim.x + threadIdx.x;
    if (i >= NNODES) return;
    float acc[NH];
#pragma unroll
    for (int f = 0; f < NH; ++f) acc[f] = 0.f;
    const float4* xr = (const float4*)(x + (long long)i * NF);
#pragma unroll 8
    for (int k4 = 0; k4 < NF / 4; ++k4) {
        float4 v = xr[k4];
        const float* wk = &w[k4 * 4 * NH];
#pragma unroll
        for (int f = 0; f < NH; ++f)
            acc[f] += v.x * wk[f] + v.y * wk[NH + f] + v.z * wk[2 * NH + f] + v.w * wk[3 * NH + f];
    }
    float di = dinv[i];
    unsigned u[8];
#pragma unroll
    for (int j = 0; j < 8; ++j)
        u[j] = bf16rne(acc[2 * j] * di) | (bf16rne(acc[2 * j + 1] * di) << 16);
    uint4* o = (uint4*)(xwn + (size_t)i * 8);
    o[0] = make_uint4(u[0], u[1], u[2], u[3]);
    o[1] = make_uint4(u[4], u[5], u[6], u[7]);
}

// ------- layer 1 pull: one wave/node, 4 lanes/edge (16 edges in flight) ----
__global__ __launch_bounds__(256) void k_edge1z(
        const uint2* __restrict__ spack, const unsigned* __restrict__ start,
        const unsigned* __restrict__ xwn, const float* __restrict__ dinv,
        const float* __restrict__ b1, const float* __restrict__ W2,
        float* __restrict__ zn) {
    int t = threadIdx.x;
    int n = blockIdx.x * 4 + (t >> 6);  // 25000 blocks * 4 waves = 100000
    int lane = t & 63;
    int fg = lane & 3, e4 = lane >> 2;
    unsigned e0 = start[n], e1 = start[n + 1];
    float ax = 0.f, ay = 0.f, az = 0.f, aw = 0.f;
    for (unsigned e = e0 + e4; e < e1; e += 16) {
        uint2 p = spack[e];
        uint2 q = *(const uint2*)(xwn + (size_t)p.x * 8 + fg * 2);
        float w = __uint_as_float(p.y);
        ax += __uint_as_float(q.x << 16) * w;
        ay += __uint_as_float(q.x & 0xffff0000u) * w;
        az += __uint_as_float(q.y << 16) * w;
        aw += __uint_as_float(q.y & 0xffff0000u) * w;
    }
#pragma unroll
    for (int m = 4; m < 64; m <<= 1) {
        ax += __shfl_xor(ax, m);
        ay += __shfl_xor(ay, m);
        az += __shfl_xor(az, m);
        aw += __shfl_xor(aw, m);
    }
    // self-loop (xwn already carries dinv[n])
    uint2 qs = *(const uint2*)(xwn + (size_t)n * 8 + fg * 2);
    ax += __uint_as_float(qs.x << 16);
    ay += __uint_as_float(qs.x & 0xffff0000u);
    az += __uint_as_float(qs.y << 16);
    aw += __uint_as_float(qs.y & 0xffff0000u);
    float di = dinv[n];
    float4 b4 = ((const float4*)b1)[fg];
    float4 w4 = ((const float4*)W2)[fg];
    float s = fmaxf(di * ax + b4.x, 0.f) * w4.x
            + fmaxf(di * ay + b4.y, 0.f) * w4.y
            + fmaxf(di * az + b4.z, 0.f) * w4.z
            + fmaxf(di * aw + b4.w, 0.f) * w4.w;
    s += __shfl_xor(s, 1);
    s += __shfl_xor(s, 2);
    if (lane == 0) zn[n] = s * di;   // store z * dinv for layer 2
}

// ------- layer 2 pull: one wave per node (64 edges in flight) --------------
__global__ __launch_bounds__(256) void k_edge2out(
        const uint2* __restrict__ spack, const unsigned* __restrict__ start,
        const float* __restrict__ zn, const float* __restrict__ dinv,
        const float* __restrict__ b2, float* __restrict__ out) {
    int t = threadIdx.x;
    int n = blockIdx.x * 4 + (t >> 6);  // 25000 blocks * 4 waves = 100000
    int lane = t & 63;
    unsigned e0 = start[n], e1 = start[n + 1];
    float acc = 0.f;
    for (unsigned e = e0 + lane; e < e1; e += 64) {
        uint2 p = spack[e];
        acc += zn[p.x] * __uint_as_float(p.y);
    }
#pragma unroll
    for (int m = 1; m < 64; m <<= 1) acc += __shfl_xor(acc, m);
    if (lane == 0) {
        float di = dinv[n];
        float v = di * acc + di * zn[n] + b2[0];
        out[n] = 1.f / (1.f + expf(-v));
    }
}

extern "C" void kernel_launch(void* const* d_in, const int* in_sizes, int n_in,
                              void* d_out, int out_size, void* d_ws, size_t ws_size,
                              hipStream_t stream) {
    const float* x  = (const float*)d_in[0];
    const int* eidx = (const int*)d_in[1];
    const float* ew = (const float*)d_in[2];
    const float* W1 = (const float*)d_in[3];
    const float* b1 = (const float*)d_in[4];
    const float* W2 = (const float*)d_in[5];
    const float* b2 = (const float*)d_in[6];
    float* out = (float*)d_out;

    const int* row = eidx;           // edge_index[0]
    const int* col = eidx + NEDGES;  // edge_index[1]

    // workspace layout (4-byte words), total ~31 MB
    unsigned* ws = (unsigned*)d_ws;
    uint2*    spack  = (uint2*)ws;                       // 3,200,000 x 8B
    unsigned* xwn    = ws + 6400000;                     //   800,000 (bf16 x 16/node)
    float*    dinv   = (float*)(ws + 7200000);           //   100,000
    float*    zn     = (float*)(ws + 7300000);           //   100,000
    unsigned* start  = ws + 7400000;                     //   100,001
    unsigned* sbase  = ws + 7500001;                     //       522
    unsigned* totals = ws + 7500523;                     //       521
    unsigned* ghist  = ws + 7501044;                     //   266,752 (NBLK*NSB)

    k_hist   <<<NBLK, 256, 0, stream>>>(col, ghist);
    k_scan1  <<<NSB, NBLK, 0, stream>>>(ghist, totals);
    k_scan2  <<<1, 256, 0, stream>>>(totals, sbase, start);
    k_scatB1 <<<NBLK, 256, 0, stream>>>(row, col, ew, ghist, sbase, spack);
    k_sortB2 <<<NSB, 256, 0, stream>>>(spack, sbase, start, dinv);
    k_xw1n   <<<(NNODES + 255) / 256, 256, 0, stream>>>(x, W1, dinv, xwn);
    k_edge1z <<<NNODES / 4, 256, 0, stream>>>(spack, start, xwn, dinv, b1, W2, zn);
    k_edge2out<<<NNODES / 4, 256, 0, stream>>>(spack, start, zn, dinv, b2, out);
}

// Round 8
// 170.852 us; speedup vs baseline: 1.1437x; 1.0421x over previous
//
#include <hip/hip_runtime.h>
#include <math.h>

#define NNODES 100000
#define NEDGES 3200000
#define NF 128
#define NH 16
#define SB 192                   // nodes per super-bucket
#define NSB 521                  // ceil(NNODES/SB)
#define NBLK 512                 // blocks for hist/scatter
#define EPB (NEDGES / NBLK)      // 6250 exact
#define CAP2 6912                // max edges/super-bucket (mean 6144, std ~78 -> +9.8 sigma)

__device__ __forceinline__ unsigned bf16rne(float f) {
    unsigned u = __float_as_uint(f);
    return (u + 0x7fffu + ((u >> 16) & 1u)) >> 16;
}

// ---------------- pass A: per-block super-bucket histogram -----------------
// ghist layout: [NBLK][NSB]  (block-contiguous)
__global__ void k_hist(const int* __restrict__ col, unsigned* __restrict__ ghist) {
    __shared__ unsigned h[NSB];
    int t = threadIdx.x, b = blockIdx.x;
    for (int i = t; i < NSB; i += 256) h[i] = 0u;
    __syncthreads();
    int e0 = b * EPB;
    for (int i = t; i < EPB; i += 256)
        atomicAdd(&h[(unsigned)col[e0 + i] / SB], 1u);
    __syncthreads();
    for (int i = t; i < NSB; i += 256) ghist[(size_t)b * NSB + i] = h[i];
}

// ---------------- scan 1: per-bucket exclusive scan across blocks ----------
__global__ __launch_bounds__(NBLK) void k_scan1(unsigned* __restrict__ ghist,
                                                unsigned* __restrict__ totals) {
    int k = blockIdx.x, t = threadIdx.x;
    __shared__ unsigned s[NBLK];
    unsigned v = ghist[(size_t)t * NSB + k];
    s[t] = v;
    __syncthreads();
    for (int off = 1; off < NBLK; off <<= 1) {
        unsigned x = (t >= off) ? s[t - off] : 0u;
        __syncthreads();
        s[t] += x;
        __syncthreads();
    }
    ghist[(size_t)t * NSB + k] = s[t] - v;  // exclusive intra-bucket offset per block
    if (t == NBLK - 1) totals[k] = s[t];
}

// ---------------- scan 2: exclusive scan of bucket totals -> sbase ---------
__global__ void k_scan2(const unsigned* __restrict__ totals, unsigned* __restrict__ sbase,
                        unsigned* __restrict__ start) {
    int t = threadIdx.x;
    __shared__ unsigned s[256];
    unsigned v[3];
    unsigned p = 0;
#pragma unroll
    for (int j = 0; j < 3; ++j) {
        int i = t * 3 + j;
        v[j] = (i < NSB) ? totals[i] : 0u;
        p += v[j];
    }
    s[t] = p;
    __syncthreads();
    for (int off = 1; off < 256; off <<= 1) {
        unsigned x = (t >= off) ? s[t - off] : 0u;
        __syncthreads();
        s[t] += x;
        __syncthreads();
    }
    unsigned run = s[t] - p;
#pragma unroll
    for (int j = 0; j < 3; ++j) {
        int i = t * 3 + j;
        if (i < NSB) sbase[i] = run;
        run += v[j];
    }
    if (t == 255) { sbase[NSB] = NEDGES; start[NNODES] = NEDGES; }
}

// ------ pass B: write-coalesced scatter (LDS-staged, onesweep style) -------
__global__ __launch_bounds__(256) void k_scatB1(
        const int* __restrict__ row, const int* __restrict__ col,
        const float* __restrict__ ew,
        const unsigned* __restrict__ ghist, const unsigned* __restrict__ sbase,
        uint2* __restrict__ spack) {
    __shared__ uint2 stage[EPB];            // 50,000 B
    __shared__ unsigned short sbArr[EPB];   // 12,500 B
    __shared__ unsigned lcnt[NSB];          //  2,084 B  (hist -> run-start counters)
    __shared__ unsigned gdelta[NSB];        //  2,084 B  (global pos = i + gdelta[sb])
    __shared__ unsigned scn[256];           //  1,024 B
    int t = threadIdx.x, b = blockIdx.x;
    int e0 = b * EPB;
    for (int i = t; i < NSB; i += 256) lcnt[i] = 0u;
    __syncthreads();
    // local histogram
    for (int i = t; i < EPB; i += 256)
        atomicAdd(&lcnt[(unsigned)col[e0 + i] / SB], 1u);
    __syncthreads();
    // exclusive scan over NSB bins (3 per thread)
    unsigned v[3];
    unsigned p = 0;
#pragma unroll
    for (int j = 0; j < 3; ++j) {
        int i = t * 3 + j;
        v[j] = (i < NSB) ? lcnt[i] : 0u;
        p += v[j];
    }
    scn[t] = p;
    __syncthreads();
    for (int off = 1; off < 256; off <<= 1) {
        unsigned x = (t >= off) ? scn[t - off] : 0u;
        __syncthreads();
        scn[t] += x;
        __syncthreads();
    }
    unsigned run = scn[t] - p;
    __syncthreads();  // all reads of lcnt done before overwrite
    unsigned lst[3];
#pragma unroll
    for (int j = 0; j < 3; ++j) {
        int i = t * 3 + j;
        if (i < NSB) {
            lst[j] = run;
            gdelta[i] = sbase[i] + ghist[(size_t)b * NSB + i] - run;
        }
        run += v[j];
    }
    __syncthreads();
#pragma unroll
    for (int j = 0; j < 3; ++j) {
        int i = t * 3 + j;
        if (i < NSB) lcnt[i] = lst[j];
    }
    __syncthreads();
    // local scatter into LDS stage
    for (int i = t; i < EPB; i += 256) {
        int e = e0 + i;
        unsigned r = (unsigned)row[e];
        unsigned c = (unsigned)col[e];
        float w = ew[e];
        unsigned sb = c / SB;
        unsigned ln = c - sb * SB;
        unsigned pos = atomicAdd(&lcnt[sb], 1u);
        stage[pos] = make_uint2(r | (ln << 17), __float_as_uint(w));
        sbArr[pos] = (unsigned short)sb;
    }
    __syncthreads();
    // coalesced write-out: consecutive lanes -> consecutive global addresses
    for (int i = t; i < EPB; i += 256)
        spack[i + gdelta[sbArr[i]]] = stage[i];
}

// ------- per-super-bucket sort to node (CSR) order ------------------------
// two coalesced reads; scatter lands in LDS; final write coalesced
__global__ __launch_bounds__(512) void k_sortB2(uint2* __restrict__ spack,
                                                const unsigned* __restrict__ sbase,
                                                unsigned* __restrict__ start,
                                                float* __restrict__ dinv) {
    __shared__ uint2 ed[CAP2];        // 55.3 KB (node-sorted payload)
    __shared__ unsigned hist[SB];
    __shared__ float wdeg[SB];
    __shared__ unsigned scn[512];
    int k = blockIdx.x, t = threadIdx.x;
    unsigned e0 = sbase[k], e1 = sbase[k + 1];
    int ne = (int)(e1 - e0);
    if (t < SB) { hist[t] = 0u; wdeg[t] = 0.f; }
    __syncthreads();
    // pass 1: coalesced read -> histogram + weighted degree
    for (int i = t; i < ne; i += 512) {
        uint2 p = spack[e0 + i];
        unsigned ln = p.x >> 17;
        atomicAdd(&hist[ln], 1u);
        atomicAdd(&wdeg[ln], __uint_as_float(p.y));
    }
    __syncthreads();
    unsigned v = (t < SB) ? hist[t] : 0u;
    scn[t] = v;
    __syncthreads();
    for (int off = 1; off < 512; off <<= 1) {
        unsigned x = (t >= off) ? scn[t - off] : 0u;
        __syncthreads();
        scn[t] += x;
        __syncthreads();
    }
    unsigned excl = scn[t] - v;
    int g = k * SB + t;
    if (t < SB && g < NNODES) {
        start[g] = e0 + excl;
        dinv[g] = rsqrtf(wdeg[t] + 1.0f);   // +1 = self-loop weight
    }
    __syncthreads();
    if (t < SB) hist[t] = excl;             // running write counters
    __syncthreads();
    // pass 2: re-read (L2-hot) -> scatter into LDS at sorted position
    for (int i = t; i < ne; i += 512) {
        uint2 p = spack[e0 + i];
        unsigned ln = p.x >> 17;
        unsigned pos = atomicAdd(&hist[ln], 1u);
        ed[pos] = make_uint2(p.x & 0x1FFFF, p.y);
    }
    __syncthreads();
    // pass 3: coalesced write-back in node order
    for (int i = t; i < ne; i += 512)
        spack[e0 + i] = ed[i];
}

// -------- xwn = bf16( (x @ W1) * dinv[i] )  [NNODES x 16, 3.2 MB] ----------
__global__ void k_xw1n(const float* __restrict__ x, const float* __restrict__ W1,
                       const float* __restrict__ dinv, unsigned* __restrict__ xwn) {
    __shared__ float w[NF * NH];
    for (int t = threadIdx.x; t < NF * NH; t += blockDim.x) w[t] = W1[t];
    __syncthreads();
    int i = blockIdx.x * blockDim.x + threadIdx.x;
    if (i >= NNODES) return;
    float acc[NH];
#pragma unroll
    for (int f = 0; f < NH; ++f) acc[f] = 0.f;
    const float4* xr = (const float4*)(x + (long long)i * NF);
#pragma unroll 8
    for (int k4 = 0; k4 < NF / 4; ++k4) {
        float4 v = xr[k4];
        const float* wk = &w[k4 * 4 * NH];
#pragma unroll
        for (int f = 0; f < NH; ++f)
            acc[f] += v.x * wk[f] + v.y * wk[NH + f] + v.z * wk[2 * NH + f] + v.w * wk[3 * NH + f];
    }
    float di = dinv[i];
    unsigned u[8];
#pragma unroll
    for (int j = 0; j < 8; ++j)
        u[j] = bf16rne(acc[2 * j] * di) | (bf16rne(acc[2 * j + 1] * di) << 16);
    uint4* o = (uint4*)(xwn + (size_t)i * 8);
    o[0] = make_uint4(u[0], u[1], u[2], u[3]);
    o[1] = make_uint4(u[4], u[5], u[6], u[7]);
}

// ------- layer 1 pull: one wave/node, 4 lanes/edge (16 edges in flight) ----
__global__ __launch_bounds__(256) void k_edge1z(
        const uint2* __restrict__ spack, const unsigned* __restrict__ start,
        const unsigned* __restrict__ xwn, const float* __restrict__ dinv,
        const float* __restrict__ b1, const float* __restrict__ W2,
        float* __restrict__ zn) {
    int t = threadIdx.x;
    int n = blockIdx.x * 4 + (t >> 6);  // 25000 blocks * 4 waves = 100000
    int lane = t & 63;
    int fg = lane & 3, e4 = lane >> 2;
    unsigned e0 = start[n], e1 = start[n + 1];
    float ax = 0.f, ay = 0.f, az = 0.f, aw = 0.f;
    for (unsigned e = e0 + e4; e < e1; e += 16) {
        uint2 p = spack[e];
        uint2 q = *(const uint2*)(xwn + (size_t)p.x * 8 + fg * 2);
        float w = __uint_as_float(p.y);
        ax += __uint_as_float(q.x << 16) * w;
        ay += __uint_as_float(q.x & 0xffff0000u) * w;
        az += __uint_as_float(q.y << 16) * w;
        aw += __uint_as_float(q.y & 0xffff0000u) * w;
    }
#pragma unroll
    for (int m = 4; m < 64; m <<= 1) {
        ax += __shfl_xor(ax, m);
        ay += __shfl_xor(ay, m);
        az += __shfl_xor(az, m);
        aw += __shfl_xor(aw, m);
    }
    // self-loop (xwn already carries dinv[n])
    uint2 qs = *(const uint2*)(xwn + (size_t)n * 8 + fg * 2);
    ax += __uint_as_float(qs.x << 16);
    ay += __uint_as_float(qs.x & 0xffff0000u);
    az += __uint_as_float(qs.y << 16);
    aw += __uint_as_float(qs.y & 0xffff0000u);
    float di = dinv[n];
    float4 b4 = ((const float4*)b1)[fg];
    float4 w4 = ((const float4*)W2)[fg];
    float s = fmaxf(di * ax + b4.x, 0.f) * w4.x
            + fmaxf(di * ay + b4.y, 0.f) * w4.y
            + fmaxf(di * az + b4.z, 0.f) * w4.z
            + fmaxf(di * aw + b4.w, 0.f) * w4.w;
    s += __shfl_xor(s, 1);
    s += __shfl_xor(s, 2);
    if (lane == 0) zn[n] = s * di;   // store z * dinv for layer 2
}

// ------- layer 2 pull: one wave per node (64 edges in flight) --------------
__global__ __launch_bounds__(256) void k_edge2out(
        const uint2* __restrict__ spack, const unsigned* __restrict__ start,
        const float* __restrict__ zn, const float* __restrict__ dinv,
        const float* __restrict__ b2, float* __restrict__ out) {
    int t = threadIdx.x;
    int n = blockIdx.x * 4 + (t >> 6);  // 25000 blocks * 4 waves = 100000
    int lane = t & 63;
    unsigned e0 = start[n], e1 = start[n + 1];
    float acc = 0.f;
    for (unsigned e = e0 + lane; e < e1; e += 64) {
        uint2 p = spack[e];
        acc += zn[p.x] * __uint_as_float(p.y);
    }
#pragma unroll
    for (int m = 1; m < 64; m <<= 1) acc += __shfl_xor(acc, m);
    if (lane == 0) {
        float di = dinv[n];
        float v = di * acc + di * zn[n] + b2[0];
        out[n] = 1.f / (1.f + expf(-v));
    }
}

extern "C" void kernel_launch(void* const* d_in, const int* in_sizes, int n_in,
                              void* d_out, int out_size, void* d_ws, size_t ws_size,
                              hipStream_t stream) {
    const float* x  = (const float*)d_in[0];
    const int* eidx = (const int*)d_in[1];
    const float* ew = (const float*)d_in[2];
    const float* W1 = (const float*)d_in[3];
    const float* b1 = (const float*)d_in[4];
    const float* W2 = (const float*)d_in[5];
    const float* b2 = (const float*)d_in[6];
    float* out = (float*)d_out;

    const int* row = eidx;           // edge_index[0]
    const int* col = eidx + NEDGES;  // edge_index[1]

    // workspace layout (4-byte words), total ~31 MB
    unsigned* ws = (unsigned*)d_ws;
    uint2*    spack  = (uint2*)ws;                       // 3,200,000 x 8B
    unsigned* xwn    = ws + 6400000;                     //   800,000 (bf16 x 16/node)
    float*    dinv   = (float*)(ws + 7200000);           //   100,000
    float*    zn     = (float*)(ws + 7300000);           //   100,000
    unsigned* start  = ws + 7400000;                     //   100,001
    unsigned* sbase  = ws + 7500001;                     //       522
    unsigned* totals = ws + 7500523;                     //       521
    unsigned* ghist  = ws + 7501044;                     //   266,752 (NBLK*NSB)

    k_hist   <<<NBLK, 256, 0, stream>>>(col, ghist);
    k_scan1  <<<NSB, NBLK, 0, stream>>>(ghist, totals);
    k_scan2  <<<1, 256, 0, stream>>>(totals, sbase, start);
    k_scatB1 <<<NBLK, 256, 0, stream>>>(row, col, ew, ghist, sbase, spack);
    k_sortB2 <<<NSB, 512, 0, stream>>>(spack, sbase, start, dinv);
    k_xw1n   <<<(NNODES + 255) / 256, 256, 0, stream>>>(x, W1, dinv, xwn);
    k_edge1z <<<NNODES / 4, 256, 0, stream>>>(spack, start, xwn, dinv, b1, W2, zn);
    k_edge2out<<<NNODES / 4, 256, 0, stream>>>(spack, start, zn, dinv, b2, out);
}

// Round 9
// 159.400 us; speedup vs baseline: 1.2259x; 1.0718x over previous
//
#include <hip/hip_runtime.h>
#include <math.h>

#define NNODES 100000
#define NEDGES 3200000
#define NF 128
#define NH 16
#define SB 192                   // nodes per super-bucket
#define NSB 521                  // ceil(NNODES/SB)
#define NBLK 512                 // blocks for hist/scatter
#define EPB (NEDGES / NBLK)      // 6250 exact
#define CAP2 6912                // max edges/super-bucket (mean 6144, std ~78 -> +9.8 sigma)

__device__ __forceinline__ unsigned bf16rne(float f) {
    unsigned u = __float_as_uint(f);
    return (u + 0x7fffu + ((u >> 16) & 1u)) >> 16;
}

// ---------------- pass A: per-block super-bucket histogram -----------------
// ghist layout: [NBLK][NSB]  (block-contiguous)
__global__ void k_hist(const int* __restrict__ col, unsigned* __restrict__ ghist) {
    __shared__ unsigned h[NSB];
    int t = threadIdx.x, b = blockIdx.x;
    for (int i = t; i < NSB; i += 256) h[i] = 0u;
    __syncthreads();
    const int2* c2 = (const int2*)(col + b * EPB);  // 25000B offsets are 8B-aligned
    for (int i = t; i < EPB / 2; i += 256) {
        int2 c = c2[i];
        atomicAdd(&h[(unsigned)c.x / SB], 1u);
        atomicAdd(&h[(unsigned)c.y / SB], 1u);
    }
    __syncthreads();
    for (int i = t; i < NSB; i += 256) ghist[(size_t)b * NSB + i] = h[i];
}

// ---------------- scan 1: per-bucket exclusive scan across blocks ----------
__global__ __launch_bounds__(NBLK) void k_scan1(unsigned* __restrict__ ghist,
                                                unsigned* __restrict__ totals) {
    int k = blockIdx.x, t = threadIdx.x;
    __shared__ unsigned s[NBLK];
    unsigned v = ghist[(size_t)t * NSB + k];
    s[t] = v;
    __syncthreads();
    for (int off = 1; off < NBLK; off <<= 1) {
        unsigned x = (t >= off) ? s[t - off] : 0u;
        __syncthreads();
        s[t] += x;
        __syncthreads();
    }
    ghist[(size_t)t * NSB + k] = s[t] - v;  // exclusive intra-bucket offset per block
    if (t == NBLK - 1) totals[k] = s[t];
}

// ---------------- scan 2: exclusive scan of bucket totals -> sbase ---------
__global__ void k_scan2(const unsigned* __restrict__ totals, unsigned* __restrict__ sbase,
                        unsigned* __restrict__ start) {
    int t = threadIdx.x;
    __shared__ unsigned s[256];
    unsigned v[3];
    unsigned p = 0;
#pragma unroll
    for (int j = 0; j < 3; ++j) {
        int i = t * 3 + j;
        v[j] = (i < NSB) ? totals[i] : 0u;
        p += v[j];
    }
    s[t] = p;
    __syncthreads();
    for (int off = 1; off < 256; off <<= 1) {
        unsigned x = (t >= off) ? s[t - off] : 0u;
        __syncthreads();
        s[t] += x;
        __syncthreads();
    }
    unsigned run = s[t] - p;
#pragma unroll
    for (int j = 0; j < 3; ++j) {
        int i = t * 3 + j;
        if (i < NSB) sbase[i] = run;
        run += v[j];
    }
    if (t == 255) { sbase[NSB] = NEDGES; start[NNODES] = NEDGES; }
}

// ------ pass B: write-coalesced scatter (LDS-staged, onesweep style) -------
__global__ __launch_bounds__(256) void k_scatB1(
        const int* __restrict__ row, const int* __restrict__ col,
        const float* __restrict__ ew,
        const unsigned* __restrict__ ghist, const unsigned* __restrict__ sbase,
        uint2* __restrict__ spack) {
    __shared__ uint2 stage[EPB];            // 50,000 B
    __shared__ unsigned short sbArr[EPB];   // 12,500 B
    __shared__ unsigned lcnt[NSB];          //  2,084 B  (hist -> run-start counters)
    __shared__ unsigned gdelta[NSB];        //  2,084 B  (global pos = i + gdelta[sb])
    __shared__ unsigned scn[256];           //  1,024 B
    int t = threadIdx.x, b = blockIdx.x;
    int e0 = b * EPB;
    for (int i = t; i < NSB; i += 256) lcnt[i] = 0u;
    __syncthreads();
    // local histogram (vectorized)
    const int2* c2 = (const int2*)(col + e0);
    for (int i = t; i < EPB / 2; i += 256) {
        int2 c = c2[i];
        atomicAdd(&lcnt[(unsigned)c.x / SB], 1u);
        atomicAdd(&lcnt[(unsigned)c.y / SB], 1u);
    }
    __syncthreads();
    // exclusive scan over NSB bins (3 per thread)
    unsigned v[3];
    unsigned p = 0;
#pragma unroll
    for (int j = 0; j < 3; ++j) {
        int i = t * 3 + j;
        v[j] = (i < NSB) ? lcnt[i] : 0u;
        p += v[j];
    }
    scn[t] = p;
    __syncthreads();
    for (int off = 1; off < 256; off <<= 1) {
        unsigned x = (t >= off) ? scn[t - off] : 0u;
        __syncthreads();
        scn[t] += x;
        __syncthreads();
    }
    unsigned run = scn[t] - p;
    __syncthreads();  // all reads of lcnt done before overwrite
    unsigned lst[3];
#pragma unroll
    for (int j = 0; j < 3; ++j) {
        int i = t * 3 + j;
        if (i < NSB) {
            lst[j] = run;
            gdelta[i] = sbase[i] + ghist[(size_t)b * NSB + i] - run;
        }
        run += v[j];
    }
    __syncthreads();
#pragma unroll
    for (int j = 0; j < 3; ++j) {
        int i = t * 3 + j;
        if (i < NSB) lcnt[i] = lst[j];
    }
    __syncthreads();
    // local scatter into LDS stage (vectorized loads, 2 edges per iteration)
    const int2* r2 = (const int2*)(row + e0);
    const float2* w2 = (const float2*)(ew + e0);
    for (int i = t; i < EPB / 2; i += 256) {
        int2 rr = r2[i];
        int2 cc = c2[i];
        float2 ww = w2[i];
        unsigned sb = (unsigned)cc.x / SB;
        unsigned ln = (unsigned)cc.x - sb * SB;
        unsigned pos = atomicAdd(&lcnt[sb], 1u);
        stage[pos] = make_uint2((unsigned)rr.x | (ln << 17), __float_as_uint(ww.x));
        sbArr[pos] = (unsigned short)sb;
        sb = (unsigned)cc.y / SB;
        ln = (unsigned)cc.y - sb * SB;
        pos = atomicAdd(&lcnt[sb], 1u);
        stage[pos] = make_uint2((unsigned)rr.y | (ln << 17), __float_as_uint(ww.y));
        sbArr[pos] = (unsigned short)sb;
    }
    __syncthreads();
    // coalesced write-out: consecutive lanes -> consecutive global addresses
    for (int i = t; i < EPB; i += 256)
        spack[i + gdelta[sbArr[i]]] = stage[i];
}

// ------- per-super-bucket sort to node (CSR) order ------------------------
// two coalesced reads; scatter lands in LDS; final write coalesced
__global__ __launch_bounds__(512) void k_sortB2(uint2* __restrict__ spack,
                                                const unsigned* __restrict__ sbase,
                                                unsigned* __restrict__ start,
                                                float* __restrict__ dinv) {
    __shared__ uint2 ed[CAP2];        // 55.3 KB (node-sorted payload)
    __shared__ unsigned hist[SB];
    __shared__ float wdeg[SB];
    __shared__ unsigned scn[512];
    int k = blockIdx.x, t = threadIdx.x;
    unsigned e0 = sbase[k], e1 = sbase[k + 1];
    int ne = (int)(e1 - e0);
    if (t < SB) { hist[t] = 0u; wdeg[t] = 0.f; }
    __syncthreads();
    // pass 1: coalesced read -> histogram + weighted degree
    for (int i = t; i < ne; i += 512) {
        uint2 p = spack[e0 + i];
        unsigned ln = p.x >> 17;
        atomicAdd(&hist[ln], 1u);
        atomicAdd(&wdeg[ln], __uint_as_float(p.y));
    }
    __syncthreads();
    unsigned v = (t < SB) ? hist[t] : 0u;
    scn[t] = v;
    __syncthreads();
    for (int off = 1; off < 512; off <<= 1) {
        unsigned x = (t >= off) ? scn[t - off] : 0u;
        __syncthreads();
        scn[t] += x;
        __syncthreads();
    }
    unsigned excl = scn[t] - v;
    int g = k * SB + t;
    if (t < SB && g < NNODES) {
        start[g] = e0 + excl;
        dinv[g] = rsqrtf(wdeg[t] + 1.0f);   // +1 = self-loop weight
    }
    __syncthreads();
    if (t < SB) hist[t] = excl;             // running write counters
    __syncthreads();
    // pass 2: re-read (L2-hot) -> scatter into LDS at sorted position
    for (int i = t; i < ne; i += 512) {
        uint2 p = spack[e0 + i];
        unsigned ln = p.x >> 17;
        unsigned pos = atomicAdd(&hist[ln], 1u);
        ed[pos] = make_uint2(p.x & 0x1FFFF, p.y);
    }
    __syncthreads();
    // pass 3: coalesced write-back in node order
    for (int i = t; i < ne; i += 512)
        spack[e0 + i] = ed[i];
}

// -------- xwn = bf16( (x @ W1) * dinv[i] )  [NNODES x 16, 3.2 MB] ----------
__global__ void k_xw1n(const float* __restrict__ x, const float* __restrict__ W1,
                       const float* __restrict__ dinv, unsigned* __restrict__ xwn) {
    __shared__ float w[NF * NH];
    for (int t = threadIdx.x; t < NF * NH; t += blockDim.x) w[t] = W1[t];
    __syncthreads();
    int i = blockIdx.x * blockDim.x + threadIdx.x;
    if (i >= NNODES) return;
    float acc[NH];
#pragma unroll
    for (int f = 0; f < NH; ++f) acc[f] = 0.f;
    const float4* xr = (const float4*)(x + (long long)i * NF);
#pragma unroll 8
    for (int k4 = 0; k4 < NF / 4; ++k4) {
        float4 v = xr[k4];
        const float* wk = &w[k4 * 4 * NH];
#pragma unroll
        for (int f = 0; f < NH; ++f)
            acc[f] += v.x * wk[f] + v.y * wk[NH + f] + v.z * wk[2 * NH + f] + v.w * wk[3 * NH + f];
    }
    float di = dinv[i];
    unsigned u[8];
#pragma unroll
    for (int j = 0; j < 8; ++j)
        u[j] = bf16rne(acc[2 * j] * di) | (bf16rne(acc[2 * j + 1] * di) << 16);
    uint4* o = (uint4*)(xwn + (size_t)i * 8);
    o[0] = make_uint4(u[0], u[1], u[2], u[3]);
    o[1] = make_uint4(u[4], u[5], u[6], u[7]);
}

// ------- layer 1 pull: one wave/node, 4 lanes/edge, 3-slot unroll ----------
// 48 edges in flight; slots 2-3 predicated (clamped row, zeroed weight)
__global__ __launch_bounds__(256) void k_edge1z(
        const uint2* __restrict__ spack, const unsigned* __restrict__ start,
        const unsigned* __restrict__ xwn, const float* __restrict__ dinv,
        const float* __restrict__ b1, const float* __restrict__ W2,
        float* __restrict__ zn) {
    int t = threadIdx.x;
    int n = blockIdx.x * 4 + (t >> 6);  // 25000 blocks * 4 waves = 100000
    int lane = t & 63;
    int fg = lane & 3, e4 = lane >> 2;
    unsigned e0 = start[n], e1 = start[n + 1];
    float ax = 0.f, ay = 0.f, az = 0.f, aw = 0.f;
    for (unsigned e = e0 + e4; e < e1; e += 48) {
        unsigned ea = e + 16, eb = e + 32;
        uint2 p0 = spack[e];
        uint2 p1 = spack[ea];   // may be past e1: stays inside ws (+pad reads land in xwn region)
        uint2 p2 = spack[eb];
        bool va = ea < e1, vb = eb < e1;
        unsigned r0 = p0.x;
        unsigned r1 = p1.x & 0x1FFFFu; r1 = r1 < NNODES ? r1 : NNODES - 1u;
        unsigned r2 = p2.x & 0x1FFFFu; r2 = r2 < NNODES ? r2 : NNODES - 1u;
        float w0 = __uint_as_float(p0.y);
        float w1 = va ? __uint_as_float(p1.y) : 0.f;
        float w2 = vb ? __uint_as_float(p2.y) : 0.f;
        uint2 q0 = *(const uint2*)(xwn + (size_t)r0 * 8 + fg * 2);
        uint2 q1 = *(const uint2*)(xwn + (size_t)r1 * 8 + fg * 2);
        uint2 q2 = *(const uint2*)(xwn + (size_t)r2 * 8 + fg * 2);
        ax += __uint_as_float(q0.x << 16) * w0 + __uint_as_float(q1.x << 16) * w1
            + __uint_as_float(q2.x << 16) * w2;
        ay += __uint_as_float(q0.x & 0xffff0000u) * w0 + __uint_as_float(q1.x & 0xffff0000u) * w1
            + __uint_as_float(q2.x & 0xffff0000u) * w2;
        az += __uint_as_float(q0.y << 16) * w0 + __uint_as_float(q1.y << 16) * w1
            + __uint_as_float(q2.y << 16) * w2;
        aw += __uint_as_float(q0.y & 0xffff0000u) * w0 + __uint_as_float(q1.y & 0xffff0000u) * w1
            + __uint_as_float(q2.y & 0xffff0000u) * w2;
    }
#pragma unroll
    for (int m = 4; m < 64; m <<= 1) {
        ax += __shfl_xor(ax, m);
        ay += __shfl_xor(ay, m);
        az += __shfl_xor(az, m);
        aw += __shfl_xor(aw, m);
    }
    // self-loop (xwn already carries dinv[n])
    uint2 qs = *(const uint2*)(xwn + (size_t)n * 8 + fg * 2);
    ax += __uint_as_float(qs.x << 16);
    ay += __uint_as_float(qs.x & 0xffff0000u);
    az += __uint_as_float(qs.y << 16);
    aw += __uint_as_float(qs.y & 0xffff0000u);
    float di = dinv[n];
    float4 b4 = ((const float4*)b1)[fg];
    float4 w4 = ((const float4*)W2)[fg];
    float s = fmaxf(di * ax + b4.x, 0.f) * w4.x
            + fmaxf(di * ay + b4.y, 0.f) * w4.y
            + fmaxf(di * az + b4.z, 0.f) * w4.z
            + fmaxf(di * aw + b4.w, 0.f) * w4.w;
    s += __shfl_xor(s, 1);
    s += __shfl_xor(s, 2);
    if (lane == 0) zn[n] = s * di;   // store z * dinv for layer 2
}

// ------- layer 2 pull: one wave per node (64 edges in flight) --------------
__global__ __launch_bounds__(256) void k_edge2out(
        const uint2* __restrict__ spack, const unsigned* __restrict__ start,
        const float* __restrict__ zn, const float* __restrict__ dinv,
        const float* __restrict__ b2, float* __restrict__ out) {
    int t = threadIdx.x;
    int n = blockIdx.x * 4 + (t >> 6);  // 25000 blocks * 4 waves = 100000
    int lane = t & 63;
    unsigned e0 = start[n], e1 = start[n + 1];
    float acc = 0.f;
    for (unsigned e = e0 + lane; e < e1; e += 64) {
        uint2 p = spack[e];
        acc += zn[p.x] * __uint_as_float(p.y);
    }
#pragma unroll
    for (int m = 1; m < 64; m <<= 1) acc += __shfl_xor(acc, m);
    if (lane == 0) {
        float di = dinv[n];
        float v = di * acc + di * zn[n] + b2[0];
        out[n] = 1.f / (1.f + expf(-v));
    }
}

extern "C" void kernel_launch(void* const* d_in, const int* in_sizes, int n_in,
                              void* d_out, int out_size, void* d_ws, size_t ws_size,
                              hipStream_t stream) {
    const float* x  = (const float*)d_in[0];
    const int* eidx = (const int*)d_in[1];
    const float* ew = (const float*)d_in[2];
    const float* W1 = (const float*)d_in[3];
    const float* b1 = (const float*)d_in[4];
    const float* W2 = (const float*)d_in[5];
    const float* b2 = (const float*)d_in[6];
    float* out = (float*)d_out;

    const int* row = eidx;           // edge_index[0]
    const int* col = eidx + NEDGES;  // edge_index[1]

    // workspace layout (4-byte words), total ~31 MB
    unsigned* ws = (unsigned*)d_ws;
    uint2*    spack  = (uint2*)ws;                       // 3,200,000 x 8B
    unsigned* xwn    = ws + 6400000;                     //   800,000 (bf16 x 16/node)
    float*    dinv   = (float*)(ws + 7200000);           //   100,000
    float*    zn     = (float*)(ws + 7300000);           //   100,000
    unsigned* start  = ws + 7400000;                     //   100,001
    unsigned* sbase  = ws + 7500001;                     //       522
    unsigned* totals = ws + 7500523;                     //       521
    unsigned* ghist  = ws + 7501044;                     //   266,752 (NBLK*NSB)

    k_hist   <<<NBLK, 256, 0, stream>>>(col, ghist);
    k_scan1  <<<NSB, NBLK, 0, stream>>>(ghist, totals);
    k_scan2  <<<1, 256, 0, stream>>>(totals, sbase, start);
    k_scatB1 <<<NBLK, 256, 0, stream>>>(row, col, ew, ghist, sbase, spack);
    k_sortB2 <<<NSB, 512, 0, stream>>>(spack, sbase, start, dinv);
    k_xw1n   <<<(NNODES + 255) / 256, 256, 0, stream>>>(x, W1, dinv, xwn);
    k_edge1z <<<NNODES / 4, 256, 0, stream>>>(spack, start, xwn, dinv, b1, W2, zn);
    k_edge2out<<<NNODES / 4, 256, 0, stream>>>(spack, start, zn, dinv, b2, out);
}